// Round 1
// baseline (215.595 us; speedup 1.0000x reference)
//
#include <hip/hip_runtime.h>
#include <stdint.h>

typedef __attribute__((ext_vector_type(8))) __bf16 bf16x8;
typedef __attribute__((ext_vector_type(4))) __bf16 bf16x4;
typedef __attribute__((ext_vector_type(4))) float f32x4;

// ---------------- gates: softmax(x @ W_aux^T + b_aux) ----------------
// one wave per row, 4 rows/block, grid 1024
__global__ __launch_bounds__(256) void k_gates(const float* __restrict__ x,
                                               const float* __restrict__ Waux,
                                               const float* __restrict__ baux,
                                               float* __restrict__ gates) {
  const int wave = threadIdx.x >> 6;
  const int lane = threadIdx.x & 63;
  const int row = blockIdx.x * 4 + wave;
  const float4* xr = (const float4*)(x + (size_t)row * 512);
  const float4* w0 = (const float4*)(Waux);
  const float4* w1 = (const float4*)(Waux + 512);
  float p0 = 0.f, p1 = 0.f;
  for (int c = lane; c < 128; c += 64) {
    float4 xv = xr[c];
    float4 a = w0[c], b = w1[c];
    p0 += xv.x * a.x + xv.y * a.y + xv.z * a.z + xv.w * a.w;
    p1 += xv.x * b.x + xv.y * b.y + xv.z * b.z + xv.w * b.w;
  }
  for (int off = 32; off; off >>= 1) {
    p0 += __shfl_down(p0, off, 64);
    p1 += __shfl_down(p1, off, 64);
  }
  if (lane == 0) {
    p0 += baux[0]; p1 += baux[1];
    float m = fmaxf(p0, p1);
    float e0 = __expf(p0 - m), e1 = __expf(p1 - m);
    float inv = 1.f / (e0 + e1);
    gates[row * 2 + 0] = e0 * inv;
    gates[row * 2 + 1] = e1 * inv;
  }
}

// ---------------- outs GEMM: C[m][n] = sum_k x[m][k] * Wflat[n][k] + bias[n] ----
// M=4096, N=512, K=512. 64x64 tiles -> grid (8,64)=512 blocks (2 blocks/CU).
// 4 waves in 2x2, each wave 32x32 via 16x16x32 mfma. XOR-swizzled LDS +
// T14 register prefetch (next K-tile loads issued before the barrier).
__global__ __launch_bounds__(256) void k_outs(const float* __restrict__ x,
                                              const float* __restrict__ W,
                                              const float* __restrict__ bias,
                                              __bf16* __restrict__ totalbf) {
  __shared__ __bf16 As[64][64];
  __shared__ __bf16 Bs[64][64];
  const int bj = blockIdx.x;   // 0..7  (N tiles of 64)
  const int bi = blockIdx.y;   // 0..63 (M tiles of 64)
  const int t = threadIdx.x;
  const int wid = t >> 6, lane = t & 63;
  const int wr = wid >> 1, wc = wid & 1;
  const int n16 = lane & 15, q = lane >> 4;
  const int sx = (n16 & 7) << 3;        // read-side swizzle (element units)
  const int erow = t >> 4;              // 0..15 (+p*16)
  const int c4 = (t & 15) << 2;         // 0..60

  f32x4 acc[2][2];
  f32x4 zero = {0.f, 0.f, 0.f, 0.f};
  for (int i = 0; i < 2; ++i)
    for (int j = 0; j < 2; ++j) acc[i][j] = zero;

  const int arow0 = bi * 64, brow0 = bj * 64;

  float4 ra[4], rb[4];
#pragma unroll
  for (int p = 0; p < 4; ++p) {
    int row = p * 16 + erow;
    ra[p] = *(const float4*)(x + (size_t)(arow0 + row) * 512 + c4);
    rb[p] = *(const float4*)(W + (size_t)(brow0 + row) * 512 + c4);
  }

  for (int kc = 0; kc < 512; kc += 64) {
    // ds_write current regs (swizzled: XOR 16B-slot index with row&7)
#pragma unroll
    for (int p = 0; p < 4; ++p) {
      int row = p * 16 + erow;
      int col = c4 ^ ((row & 7) << 3);
      float4 va = ra[p];
      bf16x4 ba = {(__bf16)va.x, (__bf16)va.y, (__bf16)va.z, (__bf16)va.w};
      *(bf16x4*)&As[row][col] = ba;
      float4 vb = rb[p];
      bf16x4 bb = {(__bf16)vb.x, (__bf16)vb.y, (__bf16)vb.z, (__bf16)vb.w};
      *(bf16x4*)&Bs[row][col] = bb;
    }
    // issue next-tile global loads (in flight during MFMA phase)
    if (kc < 448) {
#pragma unroll
      for (int p = 0; p < 4; ++p) {
        int row = p * 16 + erow;
        ra[p] = *(const float4*)(x + (size_t)(arow0 + row) * 512 + kc + 64 + c4);
        rb[p] = *(const float4*)(W + (size_t)(brow0 + row) * 512 + kc + 64 + c4);
      }
    }
    __syncthreads();
#pragma unroll
    for (int ks = 0; ks < 2; ++ks) {
      bf16x8 af[2], bfr[2];
#pragma unroll
      for (int f = 0; f < 2; ++f) {
        af[f]  = *(const bf16x8*)&As[wr * 32 + f * 16 + n16][(ks * 32 + q * 8) ^ sx];
        bfr[f] = *(const bf16x8*)&Bs[wc * 32 + f * 16 + n16][(ks * 32 + q * 8) ^ sx];
      }
      for (int fr = 0; fr < 2; ++fr)
        for (int fc = 0; fc < 2; ++fc)
          acc[fr][fc] = __builtin_amdgcn_mfma_f32_16x16x32_bf16(af[fr], bfr[fc], acc[fr][fc], 0, 0, 0);
    }
    __syncthreads();
  }

  // epilogue: +bias, write bf16 total (row = l*4096 + m, col = o)
  for (int fc = 0; fc < 2; ++fc) {
    int n_g = bj * 64 + wc * 32 + fc * 16 + n16;   // 0..511
    float bv = bias[n_g];
    int l = n_g >> 8, o = n_g & 255;
    for (int fr = 0; fr < 2; ++fr) {
      for (int r = 0; r < 4; ++r) {
        int m_g = bi * 64 + wr * 32 + fr * 16 + q * 4 + r;
        float v = acc[fr][fc][r] + bv;
        totalbf[(size_t)(l * 4096 + m_g) * 256 + o] = (__bf16)v;
      }
    }
  }
}

// ---------------- sq[i] = sum_k total[i][k]^2 ; colsum[k] = sum_i total[i][k] ----
// 256 blocks x 256 threads; block handles 32 rows (wave w: rows blk*32+w*8..+8)
__global__ __launch_bounds__(256) void k_sq(const __bf16* __restrict__ tot,
                                            float* __restrict__ sq,
                                            float* __restrict__ colsum) {
  __shared__ float lcol[4][256];
  const int t = threadIdx.x;
  const int wave = t >> 6, lane = t & 63;
  float c0 = 0.f, c1 = 0.f, c2 = 0.f, c3 = 0.f;
  for (int it = 0; it < 8; ++it) {
    int row = blockIdx.x * 32 + wave * 8 + it;
    bf16x4 v = *(const bf16x4*)(tot + (size_t)row * 256 + lane * 4);
    float f0 = v[0], f1 = v[1], f2 = v[2], f3 = v[3];
    float s = f0 * f0 + f1 * f1 + f2 * f2 + f3 * f3;
    for (int off = 32; off; off >>= 1) s += __shfl_down(s, off, 64);
    if (lane == 0) sq[row] = s;
    c0 += f0; c1 += f1; c2 += f2; c3 += f3;
  }
  lcol[wave][lane * 4 + 0] = c0;
  lcol[wave][lane * 4 + 1] = c1;
  lcol[wave][lane * 4 + 2] = c2;
  lcol[wave][lane * 4 + 3] = c3;
  __syncthreads();
  float s2 = lcol[0][t] + lcol[1][t] + lcol[2][t] + lcol[3][t];
  atomicAdd(&colsum[t], s2);
}

// ---------------- bandwidth: sum(dist) = 2n*sum(sq) - 2*||colsum||^2 ----------
__global__ __launch_bounds__(256) void k_bw(const float* __restrict__ sq,
                                            const float* __restrict__ colsum,
                                            float* __restrict__ scal) {
  __shared__ float red[256];
  const int t = threadIdx.x;
  float s = 0.f;
  for (int i = t; i < 8192; i += 256) s += sq[i];
  red[t] = s;
  __syncthreads();
  for (int off = 128; off; off >>= 1) { if (t < off) red[t] += red[t + off]; __syncthreads(); }
  float sumsq = red[0];
  __syncthreads();
  float c = colsum[t];
  red[t] = c * c;
  __syncthreads();
  for (int off = 128; off; off >>= 1) { if (t < off) red[t] += red[t + off]; __syncthreads(); }
  if (t == 0) {
    double sumdist = 2.0 * 8192.0 * (double)sumsq - 2.0 * (double)red[0];
    double bw = sumdist / (8192.0 * 8192.0 - 8192.0) / 4.0;   // / KERNEL_MUL^(5//2)
    scal[1] = (float)(1.4426950408889634 / (bw * 16.0));      // g4 * log2(e)
    scal[2] = (float)bw;
  }
}

// ---------------- combine[b][o] = g0*outs0 + g1*outs1 ------------------------
__global__ __launch_bounds__(256) void k_combine(const __bf16* __restrict__ tot,
                                                 const float* __restrict__ gates,
                                                 float* __restrict__ out) {
  int idx = blockIdx.x * 256 + threadIdx.x;   // 0..262143, 4 outputs each
  int b = idx >> 6;
  int oc = (idx & 63) * 4;
  float g0 = gates[b * 2], g1 = gates[b * 2 + 1];
  bf16x4 v0 = *(const bf16x4*)(tot + (size_t)b * 256 + oc);
  bf16x4 v1 = *(const bf16x4*)(tot + (size_t)(4096 + b) * 256 + oc);
  float4 r;
  r.x = g0 * (float)v0[0] + g1 * (float)v1[0];
  r.y = g0 * (float)v0[1] + g1 * (float)v1[1];
  r.z = g0 * (float)v0[2] + g1 * (float)v1[2];
  r.w = g0 * (float)v0[3] + g1 * (float)v1[3];
  *(float4*)(out + (size_t)b * 256 + oc) = r;
}

// ---------------- Gram tiles + fused multi-bandwidth kernel sum ---------------
// tile (ti,tj), ti<=tj only (symmetric), 128x128 per block, K=256.
// dist = sq[i]+sq[j]-2*dot ; ksum = u+u^2+u^4+u^8+u^16, u = exp(-dist*g4)
// sign uniform per tile; weight 2 off-diagonal, 1 on diagonal.
// XOR-swizzled LDS (kills the 16-way ds_read_b128 bank conflict) +
// T14 register prefetch of the next K-tile.
__global__ __launch_bounds__(256) void k_gram(const __bf16* __restrict__ tot,
                                              const float* __restrict__ sq,
                                              const float* __restrict__ scal,
                                              float* __restrict__ Ssum) {
  const int tj = blockIdx.x, ti = blockIdx.y;
  if (tj < ti) return;
  __shared__ __bf16 As[128][64];
  __shared__ __bf16 Bs[128][64];
  __shared__ float sqi[128], sqj[128];
  __shared__ float wred[4];
  const int t = threadIdx.x;
  const int wid = t >> 6, lane = t & 63;
  const int wr = wid >> 1, wc = wid & 1;
  const int n16 = lane & 15, q = lane >> 4;
  const int sx = (n16 & 7) << 3;     // read-side swizzle (element units)
  const int erow = t >> 3;           // 0..31 (+p*32)
  const int c8 = (t & 7) << 3;       // 0..56

  if (t < 128) sqi[t] = sq[ti * 128 + t];
  else         sqj[t - 128] = sq[tj * 128 + (t - 128)];

  f32x4 acc[4][4];
  f32x4 zero = {0.f, 0.f, 0.f, 0.f};
  for (int i = 0; i < 4; ++i)
    for (int j = 0; j < 4; ++j) acc[i][j] = zero;

  const int arow0 = ti * 128, brow0 = tj * 128;

  uint4 ra[4], rb[4];
#pragma unroll
  for (int p = 0; p < 4; ++p) {
    int row = p * 32 + erow;
    ra[p] = *(const uint4*)(tot + (size_t)(arow0 + row) * 256 + c8);
    rb[p] = *(const uint4*)(tot + (size_t)(brow0 + row) * 256 + c8);
  }

  for (int kc = 0; kc < 256; kc += 64) {
    // ds_write current regs (swizzled)
#pragma unroll
    for (int p = 0; p < 4; ++p) {
      int row = p * 32 + erow;
      int col = c8 ^ ((row & 7) << 3);
      *(uint4*)&As[row][col] = ra[p];
      *(uint4*)&Bs[row][col] = rb[p];
    }
    // issue next-tile global loads (fly during the MFMA phase)
    if (kc < 192) {
#pragma unroll
      for (int p = 0; p < 4; ++p) {
        int row = p * 32 + erow;
        ra[p] = *(const uint4*)(tot + (size_t)(arow0 + row) * 256 + kc + 64 + c8);
        rb[p] = *(const uint4*)(tot + (size_t)(brow0 + row) * 256 + kc + 64 + c8);
      }
    }
    __syncthreads();
#pragma unroll
    for (int ks = 0; ks < 2; ++ks) {
      bf16x8 af[4], bfr[4];
#pragma unroll
      for (int f = 0; f < 4; ++f) {
        af[f]  = *(const bf16x8*)&As[wr * 64 + f * 16 + n16][(ks * 32 + q * 8) ^ sx];
        bfr[f] = *(const bf16x8*)&Bs[wc * 64 + f * 16 + n16][(ks * 32 + q * 8) ^ sx];
      }
      for (int fr = 0; fr < 4; ++fr)
        for (int fc = 0; fc < 4; ++fc)
          acc[fr][fc] = __builtin_amdgcn_mfma_f32_16x16x32_bf16(af[fr], bfr[fc], acc[fr][fc], 0, 0, 0);
    }
    __syncthreads();
  }

  const float g = scal[1];
  float lsum = 0.f;
  for (int fr = 0; fr < 4; ++fr) {
    for (int r = 0; r < 4; ++r) {
      float si = sqi[wr * 64 + fr * 16 + q * 4 + r];
      for (int fc = 0; fc < 4; ++fc) {
        float sj = sqj[wc * 64 + fc * 16 + n16];
        float dist = si + sj - 2.f * acc[fr][fc][r];
        float e = exp2f(-dist * g);
        float e2 = e * e, e4 = e2 * e2, e8 = e4 * e4, e16 = e8 * e8;
        lsum += e + e2 + e4 + e8 + e16;
      }
    }
  }
  for (int off = 32; off; off >>= 1) lsum += __shfl_down(lsum, off, 64);
  if (lane == 0) wred[wid] = lsum;
  __syncthreads();
  if (t == 0) {
    float blocksum = wred[0] + wred[1] + wred[2] + wred[3];
    float sgn = ((ti < 32) == (tj < 32)) ? 1.f : -1.f;
    float wgt = (ti == tj) ? sgn : 2.f * sgn;
    atomicAdd(Ssum, wgt * blocksum);
  }
}

// ---------------- final scalar: -mean = -S / B^2 ------------------------------
__global__ void k_final(const float* __restrict__ scal, float* __restrict__ out) {
  out[1048576] = -(scal[0] / 16777216.0f);
}

extern "C" void kernel_launch(void* const* d_in, const int* in_sizes, int n_in,
                              void* d_out, int out_size, void* d_ws, size_t ws_size,
                              hipStream_t stream) {
  const float* x    = (const float*)d_in[0];
  const float* Waux = (const float*)d_in[1];
  const float* baux = (const float*)d_in[2];
  const float* W    = (const float*)d_in[3];
  const float* bias = (const float*)d_in[4];
  float* out = (float*)d_out;

  char* ws = (char*)d_ws;
  __bf16* totalbf = (__bf16*)ws;                    // 8192*256*2 = 4,194,304 B
  float* sq      = (float*)(ws + 4194304);          // 8192 f32
  float* colsum  = (float*)(ws + 4227072);          // 256 f32
  float* scal    = (float*)(ws + 4228096);          // [0]=Ssum [1]=g4l2 [2]=bw
  float* gates   = (float*)(ws + 4228160);          // 4096*2 f32

  // zero the atomic accumulators (colsum + scalars); ws is poisoned each launch
  hipMemsetAsync(ws + 4227072, 0, 1024 + 64, stream);

  k_gates<<<1024, 256, 0, stream>>>(x, Waux, baux, gates);
  k_outs<<<dim3(8, 64), 256, 0, stream>>>(x, W, bias, totalbf);
  k_sq<<<256, 256, 0, stream>>>(totalbf, sq, colsum);
  k_bw<<<1, 256, 0, stream>>>(sq, colsum, scal);
  k_combine<<<1024, 256, 0, stream>>>(totalbf, gates, out);
  k_gram<<<dim3(64, 64), 256, 0, stream>>>(totalbf, sq, scal, scal);
  k_final<<<1, 1, 0, stream>>>(scal, out);
}

// Round 2
// 151.409 us; speedup vs baseline: 1.4239x; 1.4239x over previous
//
#include <hip/hip_runtime.h>
#include <stdint.h>
#include <math.h>

typedef __attribute__((ext_vector_type(8))) __bf16 bf16x8;
typedef __attribute__((ext_vector_type(4))) __bf16 bf16x4;
typedef __attribute__((ext_vector_type(4))) float f32x4;

// async global->LDS 16B DMA (no VGPR round-trip). LDS dest must be
// wave-uniform base; HW writes lane i at base + i*16.
__device__ __forceinline__ void gload_lds16(const __bf16* g, __bf16* l) {
  __builtin_amdgcn_global_load_lds(
      (const __attribute__((address_space(1))) unsigned int*)g,
      (__attribute__((address_space(3))) unsigned int*)l,
      16, 0, 0);
}

// ---------------- gates: softmax(x @ W_aux^T + b_aux) ----------------
// one wave per row, 4 rows/block, grid 1024
__global__ __launch_bounds__(256) void k_gates(const float* __restrict__ x,
                                               const float* __restrict__ Waux,
                                               const float* __restrict__ baux,
                                               float* __restrict__ gates) {
  const int wave = threadIdx.x >> 6;
  const int lane = threadIdx.x & 63;
  const int row = blockIdx.x * 4 + wave;
  const float4* xr = (const float4*)(x + (size_t)row * 512);
  const float4* w0 = (const float4*)(Waux);
  const float4* w1 = (const float4*)(Waux + 512);
  float p0 = 0.f, p1 = 0.f;
  for (int c = lane; c < 128; c += 64) {
    float4 xv = xr[c];
    float4 a = w0[c], b = w1[c];
    p0 += xv.x * a.x + xv.y * a.y + xv.z * a.z + xv.w * a.w;
    p1 += xv.x * b.x + xv.y * b.y + xv.z * b.z + xv.w * b.w;
  }
  for (int off = 32; off; off >>= 1) {
    p0 += __shfl_down(p0, off, 64);
    p1 += __shfl_down(p1, off, 64);
  }
  if (lane == 0) {
    p0 += baux[0]; p1 += baux[1];
    float m = fmaxf(p0, p1);
    float e0 = __expf(p0 - m), e1 = __expf(p1 - m);
    float inv = 1.f / (e0 + e1);
    gates[row * 2 + 0] = e0 * inv;
    gates[row * 2 + 1] = e1 * inv;
  }
}

// ---------------- outs GEMM: C[m][n] = sum_k x[m][k] * Wflat[n][k] + bias[n] ----
// M=4096, N=512, K=512. 64x64 tiles -> grid (8,64)=512 blocks (2 blocks/CU).
// 4 waves in 2x2, each wave 32x32 via 16x16x32 mfma. XOR-swizzled LDS +
// register prefetch (small live set: acc is only 16 VGPRs here, no spill).
__global__ __launch_bounds__(256) void k_outs(const float* __restrict__ x,
                                              const float* __restrict__ W,
                                              const float* __restrict__ bias,
                                              __bf16* __restrict__ totalbf) {
  __shared__ __bf16 As[64][64];
  __shared__ __bf16 Bs[64][64];
  const int bj = blockIdx.x;   // 0..7  (N tiles of 64)
  const int bi = blockIdx.y;   // 0..63 (M tiles of 64)
  const int t = threadIdx.x;
  const int wid = t >> 6, lane = t & 63;
  const int wr = wid >> 1, wc = wid & 1;
  const int n16 = lane & 15, q = lane >> 4;
  const int sx = (n16 & 7) << 3;        // read-side swizzle (element units)
  const int erow = t >> 4;              // 0..15 (+p*16)
  const int c4 = (t & 15) << 2;         // 0..60

  f32x4 acc[2][2];
  f32x4 zero = {0.f, 0.f, 0.f, 0.f};
  for (int i = 0; i < 2; ++i)
    for (int j = 0; j < 2; ++j) acc[i][j] = zero;

  const int arow0 = bi * 64, brow0 = bj * 64;

  float4 ra[4], rb[4];
#pragma unroll
  for (int p = 0; p < 4; ++p) {
    int row = p * 16 + erow;
    ra[p] = *(const float4*)(x + (size_t)(arow0 + row) * 512 + c4);
    rb[p] = *(const float4*)(W + (size_t)(brow0 + row) * 512 + c4);
  }

  for (int kc = 0; kc < 512; kc += 64) {
    // ds_write current regs (swizzled: XOR 16B-slot index with row&7)
#pragma unroll
    for (int p = 0; p < 4; ++p) {
      int row = p * 16 + erow;
      int col = c4 ^ ((row & 7) << 3);
      float4 va = ra[p];
      bf16x4 ba = {(__bf16)va.x, (__bf16)va.y, (__bf16)va.z, (__bf16)va.w};
      *(bf16x4*)&As[row][col] = ba;
      float4 vb = rb[p];
      bf16x4 bb = {(__bf16)vb.x, (__bf16)vb.y, (__bf16)vb.z, (__bf16)vb.w};
      *(bf16x4*)&Bs[row][col] = bb;
    }
    // issue next-tile global loads (in flight during MFMA phase)
    if (kc < 448) {
#pragma unroll
      for (int p = 0; p < 4; ++p) {
        int row = p * 16 + erow;
        ra[p] = *(const float4*)(x + (size_t)(arow0 + row) * 512 + kc + 64 + c4);
        rb[p] = *(const float4*)(W + (size_t)(brow0 + row) * 512 + kc + 64 + c4);
      }
    }
    __syncthreads();
#pragma unroll
    for (int ks = 0; ks < 2; ++ks) {
      bf16x8 af[2], bfr[2];
#pragma unroll
      for (int f = 0; f < 2; ++f) {
        af[f]  = *(const bf16x8*)&As[wr * 32 + f * 16 + n16][(ks * 32 + q * 8) ^ sx];
        bfr[f] = *(const bf16x8*)&Bs[wc * 32 + f * 16 + n16][(ks * 32 + q * 8) ^ sx];
      }
      for (int fr = 0; fr < 2; ++fr)
        for (int fc = 0; fc < 2; ++fc)
          acc[fr][fc] = __builtin_amdgcn_mfma_f32_16x16x32_bf16(af[fr], bfr[fc], acc[fr][fc], 0, 0, 0);
    }
    __syncthreads();
  }

  // epilogue: +bias, write bf16 total (row = l*4096 + m, col = o)
  for (int fc = 0; fc < 2; ++fc) {
    int n_g = bj * 64 + wc * 32 + fc * 16 + n16;   // 0..511
    float bv = bias[n_g];
    int l = n_g >> 8, o = n_g & 255;
    for (int fr = 0; fr < 2; ++fr) {
      for (int r = 0; r < 4; ++r) {
        int m_g = bi * 64 + wr * 32 + fr * 16 + q * 4 + r;
        float v = acc[fr][fc][r] + bv;
        totalbf[(size_t)(l * 4096 + m_g) * 256 + o] = (__bf16)v;
      }
    }
  }
}

// ---------------- sq[i] = sum_k total[i][k]^2 ; colsum[k] = sum_i total[i][k] ----
__global__ __launch_bounds__(256) void k_sq(const __bf16* __restrict__ tot,
                                            float* __restrict__ sq,
                                            float* __restrict__ colsum) {
  __shared__ float lcol[4][256];
  const int t = threadIdx.x;
  const int wave = t >> 6, lane = t & 63;
  float c0 = 0.f, c1 = 0.f, c2 = 0.f, c3 = 0.f;
  for (int it = 0; it < 8; ++it) {
    int row = blockIdx.x * 32 + wave * 8 + it;
    bf16x4 v = *(const bf16x4*)(tot + (size_t)row * 256 + lane * 4);
    float f0 = v[0], f1 = v[1], f2 = v[2], f3 = v[3];
    float s = f0 * f0 + f1 * f1 + f2 * f2 + f3 * f3;
    for (int off = 32; off; off >>= 1) s += __shfl_down(s, off, 64);
    if (lane == 0) sq[row] = s;
    c0 += f0; c1 += f1; c2 += f2; c3 += f3;
  }
  lcol[wave][lane * 4 + 0] = c0;
  lcol[wave][lane * 4 + 1] = c1;
  lcol[wave][lane * 4 + 2] = c2;
  lcol[wave][lane * 4 + 3] = c3;
  __syncthreads();
  float s2 = lcol[0][t] + lcol[1][t] + lcol[2][t] + lcol[3][t];
  atomicAdd(&colsum[t], s2);
}

// ---------------- bandwidth: sum(dist) = 2n*sum(sq) - 2*||colsum||^2 ----------
__global__ __launch_bounds__(256) void k_bw(const float* __restrict__ sq,
                                            const float* __restrict__ colsum,
                                            float* __restrict__ scal) {
  __shared__ float red[256];
  const int t = threadIdx.x;
  float s = 0.f;
  for (int i = t; i < 8192; i += 256) s += sq[i];
  red[t] = s;
  __syncthreads();
  for (int off = 128; off; off >>= 1) { if (t < off) red[t] += red[t + off]; __syncthreads(); }
  float sumsq = red[0];
  __syncthreads();
  float c = colsum[t];
  red[t] = c * c;
  __syncthreads();
  for (int off = 128; off; off >>= 1) { if (t < off) red[t] += red[t + off]; __syncthreads(); }
  if (t == 0) {
    double sumdist = 2.0 * 8192.0 * (double)sumsq - 2.0 * (double)red[0];
    double bw = sumdist / (8192.0 * 8192.0 - 8192.0) / 4.0;   // / KERNEL_MUL^(5//2)
    scal[1] = (float)(1.4426950408889634 / (bw * 16.0));      // g4 * log2(e)
    scal[2] = (float)bw;
  }
}

// ---------------- combine[b][o] = g0*outs0 + g1*outs1 ------------------------
__global__ __launch_bounds__(256) void k_combine(const __bf16* __restrict__ tot,
                                                 const float* __restrict__ gates,
                                                 float* __restrict__ out) {
  int idx = blockIdx.x * 256 + threadIdx.x;   // 0..262143, 4 outputs each
  int b = idx >> 6;
  int oc = (idx & 63) * 4;
  float g0 = gates[b * 2], g1 = gates[b * 2 + 1];
  bf16x4 v0 = *(const bf16x4*)(tot + (size_t)b * 256 + oc);
  bf16x4 v1 = *(const bf16x4*)(tot + (size_t)(4096 + b) * 256 + oc);
  float4 r;
  r.x = g0 * (float)v0[0] + g1 * (float)v1[0];
  r.y = g0 * (float)v0[1] + g1 * (float)v1[1];
  r.z = g0 * (float)v0[2] + g1 * (float)v1[2];
  r.w = g0 * (float)v0[3] + g1 * (float)v1[3];
  *(float4*)(out + (size_t)b * 256 + oc) = r;
}

// ---------------- Gram tiles + fused multi-bandwidth kernel sum ---------------
// Compact upper-triangle launch: 2080 blocks (= 8 XCDs x 260, perfectly
// balanced), XCD-chunked so consecutive tiles on one XCD share the A-panel.
// 128x128 tile, K=256. Staging via global_load_lds (async DMA, 0 VGPRs) with
// pre-swizzled global source; LDS double-buffer: issue next chunk's DMA,
// compute current, one __syncthreads (implicit vmcnt(0) drains prefetch).
// Read-side XOR swizzle keeps ds_read_b128 conflict-free.
__global__ __launch_bounds__(256) void k_gram(const __bf16* __restrict__ tot,
                                              const float* __restrict__ sq,
                                              const float* __restrict__ scal,
                                              float* __restrict__ Ssum) {
  // ---- block id -> (ti,tj), ti<=tj ----
  const int b = blockIdx.x;                    // 0..2079
  const int nid = (b & 7) * 260 + (b >> 3);    // XCD-chunked, bijective (2080=8*260)
  int ti = (int)((129.0 - sqrt(129.0 * 129.0 - 8.0 * (double)nid)) * 0.5);
  while (64 * ti - ti * (ti - 1) / 2 > nid) --ti;
  while (64 * (ti + 1) - (ti + 1) * ti / 2 <= nid) ++ti;
  const int tj = ti + (nid - (64 * ti - ti * (ti - 1) / 2));

  __shared__ __bf16 As[2][128][64];
  __shared__ __bf16 Bs[2][128][64];
  __shared__ float sqi[128], sqj[128];
  __shared__ float wred[4];
  const int t = threadIdx.x;
  const int wid = t >> 6, lane = t & 63;
  const int wr = wid >> 1, wc = wid & 1;
  const int n16 = lane & 15, q = lane >> 4;
  const int sx = (n16 & 7) << 3;     // read-side swizzle (element units)
  const int lr = lane >> 3;          // 0..7: row within 8-row DMA chunk
  const int ls = lane & 7;           // 0..7: 16B slot within row

  if (t < 128) sqi[t] = sq[ti * 128 + t];
  else         sqj[t - 128] = sq[tj * 128 + (t - 128)];

  f32x4 acc[4][4];
  f32x4 zero = {0.f, 0.f, 0.f, 0.f};
  for (int i = 0; i < 4; ++i)
    for (int j = 0; j < 4; ++j) acc[i][j] = zero;

  // pre-swizzled per-lane global source: LDS slot ls of row r gets global
  // slot ls^(r&7); here r&7 == lr for every chunk (rows step by 8).
  const __bf16* gA = tot + (size_t)(ti * 128 + wid * 32 + lr) * 256 + ((ls ^ lr) << 3);
  const __bf16* gB = tot + (size_t)(tj * 128 + wid * 32 + lr) * 256 + ((ls ^ lr) << 3);

  // prologue: stage chunk 0 into buffer 0 (wave wid covers rows wid*32..+32)
#pragma unroll
  for (int p = 0; p < 4; ++p) {
    gload_lds16(gA + p * 8 * 256, &As[0][wid * 32 + p * 8][0]);
    gload_lds16(gB + p * 8 * 256, &Bs[0][wid * 32 + p * 8][0]);
  }
  __syncthreads();   // implicit vmcnt(0): buffer 0 ready

  int buf = 0;
  for (int it = 0; it < 4; ++it) {
    // issue async DMA for next K-chunk into the other buffer
    if (it < 3) {
      const int kc = (it + 1) * 64;
#pragma unroll
      for (int p = 0; p < 4; ++p) {
        gload_lds16(gA + p * 8 * 256 + kc, &As[buf ^ 1][wid * 32 + p * 8][0]);
        gload_lds16(gB + p * 8 * 256 + kc, &Bs[buf ^ 1][wid * 32 + p * 8][0]);
      }
    }
    // compute current buffer (loads fly under the MFMAs)
#pragma unroll
    for (int ks = 0; ks < 2; ++ks) {
      bf16x8 af[4], bfr[4];
#pragma unroll
      for (int f = 0; f < 4; ++f) {
        af[f]  = *(const bf16x8*)&As[buf][wr * 64 + f * 16 + n16][(ks * 32 + q * 8) ^ sx];
        bfr[f] = *(const bf16x8*)&Bs[buf][wc * 64 + f * 16 + n16][(ks * 32 + q * 8) ^ sx];
      }
      for (int fr = 0; fr < 4; ++fr)
        for (int fc = 0; fc < 4; ++fc)
          acc[fr][fc] = __builtin_amdgcn_mfma_f32_16x16x32_bf16(af[fr], bfr[fc], acc[fr][fc], 0, 0, 0);
    }
    __syncthreads();   // drains prefetch DMA (vmcnt 0) + protects buffer reuse
    buf ^= 1;
  }

  const float g = scal[1];
  float lsum = 0.f;
  for (int fr = 0; fr < 4; ++fr) {
    for (int r = 0; r < 4; ++r) {
      float si = sqi[wr * 64 + fr * 16 + q * 4 + r];
      for (int fc = 0; fc < 4; ++fc) {
        float sj = sqj[wc * 64 + fc * 16 + n16];
        float dist = si + sj - 2.f * acc[fr][fc][r];
        float e = exp2f(-dist * g);
        float e2 = e * e, e4 = e2 * e2, e8 = e4 * e4, e16 = e8 * e8;
        lsum += e + e2 + e4 + e8 + e16;
      }
    }
  }
  for (int off = 32; off; off >>= 1) lsum += __shfl_down(lsum, off, 64);
  if (lane == 0) wred[wid] = lsum;
  __syncthreads();
  if (t == 0) {
    float blocksum = wred[0] + wred[1] + wred[2] + wred[3];
    float sgn = ((ti < 32) == (tj < 32)) ? 1.f : -1.f;
    float wgt = (ti == tj) ? sgn : 2.f * sgn;
    atomicAdd(Ssum, wgt * blocksum);
  }
}

// ---------------- final scalar: -mean = -S / B^2 ------------------------------
__global__ void k_final(const float* __restrict__ scal, float* __restrict__ out) {
  out[1048576] = -(scal[0] / 16777216.0f);
}

extern "C" void kernel_launch(void* const* d_in, const int* in_sizes, int n_in,
                              void* d_out, int out_size, void* d_ws, size_t ws_size,
                              hipStream_t stream) {
  const float* x    = (const float*)d_in[0];
  const float* Waux = (const float*)d_in[1];
  const float* baux = (const float*)d_in[2];
  const float* W    = (const float*)d_in[3];
  const float* bias = (const float*)d_in[4];
  float* out = (float*)d_out;

  char* ws = (char*)d_ws;
  __bf16* totalbf = (__bf16*)ws;                    // 8192*256*2 = 4,194,304 B
  float* sq      = (float*)(ws + 4194304);          // 8192 f32
  float* colsum  = (float*)(ws + 4227072);          // 256 f32
  float* scal    = (float*)(ws + 4228096);          // [0]=Ssum [1]=g4l2 [2]=bw
  float* gates   = (float*)(ws + 4228160);          // 4096*2 f32

  // zero the atomic accumulators (colsum + scalars); ws is poisoned each launch
  hipMemsetAsync(ws + 4227072, 0, 1024 + 64, stream);

  k_gates<<<1024, 256, 0, stream>>>(x, Waux, baux, gates);
  k_outs<<<dim3(8, 64), 256, 0, stream>>>(x, W, bias, totalbf);
  k_sq<<<256, 256, 0, stream>>>(totalbf, sq, colsum);
  k_bw<<<1, 256, 0, stream>>>(sq, colsum, scal);
  k_combine<<<1024, 256, 0, stream>>>(totalbf, gates, out);
  k_gram<<<2080, 256, 0, stream>>>(totalbf, sq, scal, scal);
  k_final<<<1, 1, 0, stream>>>(scal, out);
}